// Round 13
// baseline (591.386 us; speedup 1.0000x reference)
//
#include <hip/hip_runtime.h>
#include <stdint.h>

// ---------------------------------------------------------------------------
// HarmonicStructureDiscriminator on MI355X (gfx950)
// STFT(512/256) -> log-shift lower (KF=7) -> conv1x7(14->64)
//   -> 8x dilated conv3x3(64->64, d=1..8) -> conv3x3(64->1)
// Round 13: R12's both-in-LDS conv3, ks-split into 6 phases so LDS/block =
// 29.8KB -> 4 blocks/CU (16 waves, ~one grid round).  R9 plane canvas
// [b][f][ks2][t][32ch] makes both staging copies LINEAR (coalesced 1KB
// wave-loads, conflict-free LDS writes); W staged fragment-major so B
// ds_reads are lane*16B (evenly bank-spread, no swizzle at all).
// R7 XCD mapping kept (bid&7 -> (b, f-half)).
// mfma_f32_16x16x32_bf16: A[m=lane&15][k=q*8+j], B[n=lane&15][k],
// D col=lane&15,row=q*4+reg (m89/m101-verified).
// ---------------------------------------------------------------------------

typedef __attribute__((ext_vector_type(8))) short bf16x8;
typedef __attribute__((ext_vector_type(4))) float f32x4;
typedef __attribute__((ext_vector_type(4))) int   i32x4;

#define HCV 273
#define TCV 273
#define NBATCH 4
#define PLANE (TCV * 32)          // 8736 elems: one [t][32ch] plane
#define FROW  (2 * PLANE)         // 17472 elems per f-row (2 ks planes)

static constexpr size_t CAN_BYTES  = (size_t)NBATCH * HCV * FROW * 2;      // 38,158,848
static constexpr size_t LOWC_BYTES = (size_t)NBATCH * HCV * TCV * 16 * 2;  // 9,539,712
static constexpr size_t SPEC_BYTES = (size_t)NBATCH * 257 * 257 * 2 * 4;
static constexpr size_t W1N_BYTES  = 64 * 128 * 2;
static constexpr size_t WLN_BYTES  = 8 * 9 * 64 * 64 * 2;
static constexpr size_t WFRAG_BYTES = 8 * 9 * 2 * 4 * 512 * 2;             // 589,824

static __device__ __forceinline__ unsigned short f2bf(float f) {
  union { float f; unsigned u; } v; v.f = f;
  unsigned r = v.u + 0x7FFFu + ((v.u >> 16) & 1u);   // RNE
  return (unsigned short)(r >> 16);
}
static __device__ __forceinline__ float bflo(int u) {
  union { unsigned u; float f; } v; v.u = ((unsigned)u) << 16; return v.f;
}
static __device__ __forceinline__ float bfhi(int u) {
  union { unsigned u; float f; } v; v.u = ((unsigned)u) & 0xFFFF0000u; return v.f;
}

// ---------------------------------------------------------------------------
// Zero ONLY the canvas halos (interior is fully overwritten each layer).
// Layout: (b,f,ks,t,32ch).
// ---------------------------------------------------------------------------
__global__ __launch_bounds__(256) void halo_zero_kernel(unsigned short* cA,
                                                        unsigned short* cB,
                                                        unsigned short* lowC) {
  int idx = blockIdx.x * 256 + threadIdx.x;
  if (idx >= NBATCH * HCV * TCV) return;
  int b = idx / (HCV * TCV);
  int pos = idx % (HCV * TCV);
  int row = pos / TCV, col = pos % TCV;
  bool halo = (row < 8) | (row > 264) | (col < 8) | (col > 264);
  if (!halo) return;
  i32x4 z = {0, 0, 0, 0};
#pragma unroll
  for (int h = 0; h < 2; h++) {
    size_t base = ((((size_t)b * HCV + row) * 2 + h) * TCV + col) * 32;
    i32x4* a = (i32x4*)(cA + base);
    i32x4* c = (i32x4*)(cB + base);
#pragma unroll
    for (int i = 0; i < 4; i++) { a[i] = z; c[i] = z; }
  }
  i32x4* l = (i32x4*)(lowC + (size_t)idx * 16);
  l[0] = z; l[1] = z;
}

// ---------------------------------------------------------------------------
// Weight normalization.
// blocks 0..63:   conv1 -> w1n[oc][k], k = kw*16+ch
// blocks 64..575: 8 layers x 64 oc -> wln[l][tap][oc][ic]  (edge path)
//                 AND wfrag fragment-major: [l][tap][ks][nt][lane][j]
// block 576:      last conv -> fp32 wlast[tap][ic]
// ---------------------------------------------------------------------------
__global__ __launch_bounds__(256) void wnorm_kernel(
    const float* v_h, const float* g_h,
    const float* vs, const float* gs,
    const float* v_last, const float* g_last,
    unsigned short* w1n, unsigned short* wln, unsigned short* wfrag,
    float* wlast) {
  __shared__ float red[256];
  int bid = blockIdx.x, tid = threadIdx.x;
  if (bid < 64) {
    int oc = bid;
    const float* v = v_h + oc * 98;       // [ch][kw] = [14][7]
    float s = 0.f;
    for (int i = tid; i < 98; i += 256) s += v[i] * v[i];
    red[tid] = s; __syncthreads();
    for (int off = 128; off > 0; off >>= 1) { if (tid < off) red[tid] += red[tid + off]; __syncthreads(); }
    float scale = g_h[oc] / sqrtf(red[0]);
    for (int k = tid; k < 128; k += 256) {
      int kw = k >> 4, ch = k & 15;
      unsigned short val = 0;
      if (kw < 7 && ch < 14) val = f2bf(v[ch * 7 + kw] * scale);
      w1n[oc * 128 + k] = val;
    }
  } else if (bid < 576) {
    int l = (bid - 64) >> 6, oc = (bid - 64) & 63;
    const float* v = vs + ((size_t)(l * 64 + oc)) * 576;  // [ic][kh][kw]
    float s = 0.f;
    for (int i = tid; i < 576; i += 256) s += v[i] * v[i];
    red[tid] = s; __syncthreads();
    for (int off = 128; off > 0; off >>= 1) { if (tid < off) red[tid] += red[tid + off]; __syncthreads(); }
    float scale = gs[l * 64 + oc] / sqrtf(red[0]);
    int nt = oc >> 4, lr = oc & 15;
    for (int i = tid; i < 576; i += 256) {
      int ic = i / 9, tap = i - ic * 9;
      unsigned short val = f2bf(v[i] * scale);
      wln[(((size_t)l * 9 + tap) * 64 + oc) * 64 + ic] = val;
      int ks = ic >> 5, qq = (ic >> 3) & 3, j = ic & 7;
      wfrag[(size_t)l * 36864 + (((tap * 2 + ks) * 4 + nt) * 512)
            + (((qq << 4) | lr) * 8) + j] = val;
    }
  } else {
    const float* v = v_last;
    float s = 0.f;
    for (int i = tid; i < 576; i += 256) s += v[i] * v[i];
    red[tid] = s; __syncthreads();
    for (int off = 128; off > 0; off >>= 1) { if (tid < off) red[tid] += red[tid + off]; __syncthreads(); }
    float scale = g_last[0] / sqrtf(red[0]);
    for (int i = tid; i < 576; i += 256) {
      int ic = i / 9, tap = i - ic * 9;
      wlast[tap * 64 + ic] = v[i] * scale;
    }
  }
}

// ---------------------------------------------------------------------------
// STFT: radix-2 DIT FFT in LDS; reflect pad + Hann fused into bit-rev load.
// ---------------------------------------------------------------------------
__global__ __launch_bounds__(256) void stft_kernel(const float* __restrict__ x,
                                                   float* __restrict__ spec) {
  __shared__ float re[512];
  __shared__ float im[512];
  int bid = blockIdx.x;
  int b = bid / 257, fr = bid % 257;
  const float* xb = x + (size_t)b * 65536;
  int tid = threadIdx.x;
  for (int ii = 0; ii < 2; ii++) {
    int n = tid + ii * 256;
    int s = __brev((unsigned)n) >> 23;
    int j = fr * 256 + s - 256;
    int ja = j < 0 ? -j : (j >= 65536 ? 131070 - j : j);
    float w = 0.5f - 0.5f * __cosf(6.283185307179586f * (float)s / 512.0f);
    re[n] = xb[ja] * w;
    im[n] = 0.f;
  }
  __syncthreads();
  for (int st = 0; st < 9; st++) {
    int half = 1 << st;
    int p = tid & (half - 1);
    int g = tid >> st;
    int i0 = (g << (st + 1)) + p;
    int i1 = i0 + half;
    float ang = -6.283185307179586f * (float)p / (float)(2 << st);
    float sv, cv; __sincosf(ang, &sv, &cv);
    float br = re[i1], bi = im[i1];
    float tr = cv * br - sv * bi;
    float ti = cv * bi + sv * br;
    float ar = re[i0], ai = im[i0];
    re[i1] = ar - tr; im[i1] = ai - ti;
    re[i0] = ar + tr; im[i0] = ai + ti;
    __syncthreads();
  }
  for (int k = tid; k < 257; k += 256) {
    float* o = spec + (((size_t)b * 257 + fr) * 257 + k) * 2;
    o[0] = re[k];
    o[1] = im[k];
  }
}

// ---------------------------------------------------------------------------
// Harmonic lowering -> lowC canvas [b][f+8][t+8][16] (ch14,15 = 0), bf16.
// ---------------------------------------------------------------------------
__global__ __launch_bounds__(256) void lower_kernel(const float* __restrict__ spec,
                                                    unsigned short* __restrict__ lowC) {
  int idx = blockIdx.x * 256 + threadIdx.x;
  if (idx >= 4 * 66049) return;
  int b = idx / 66049, r = idx % 66049, f = r / 257, t = r % 257;
  const float shifts[7] = {1945.9101090932196f, 1252.7629684953681f, 847.2978603872037f,
                           559.6157879354227f, 336.4722366212129f, 154.15067982725836f, 0.0f};
  const float* sp = spec + ((size_t)(b * 257 + t)) * 257 * 2;
  unsigned short* lp = lowC + (((size_t)b * HCV + f + 8) * TCV + t + 8) * 16;
  unsigned w[8];
  for (int kf = 0; kf < 7; kf++) {
    float src = (float)f - shifts[kf];
    float lo = floorf(src);
    int li = (int)lo;
    float fr = src - lo;
    float g0r = 0.f, g0i = 0.f, g1r = 0.f, g1i = 0.f;
    if (li >= 0 && li < 257) { g0r = sp[li * 2]; g0i = sp[li * 2 + 1]; }
    if (li + 1 >= 0 && li + 1 < 257) { g1r = sp[(li + 1) * 2]; g1i = sp[(li + 1) * 2 + 1]; }
    float vr = (1.f - fr) * g0r + fr * g1r;
    float vi = (1.f - fr) * g0i + fr * g1i;
    w[kf] = (unsigned)f2bf(vr) | ((unsigned)f2bf(vi) << 16);
  }
  w[7] = 0;
  ((i32x4*)lp)[0] = i32x4{(int)w[0], (int)w[1], (int)w[2], (int)w[3]};
  ((i32x4*)lp)[1] = i32x4{(int)w[4], (int)w[5], (int)w[6], (int)w[7]};
}

// ---------------------------------------------------------------------------
// conv1: 14->64, 1x7, pad 3.  Block = (b,f) row.  B in registers (from
// swizzled LDS), A direct from global (im2col rows contiguous in NHWC16).
// Writes canvas layout (b,f,ks,t,32ch).
// ---------------------------------------------------------------------------
__global__ __launch_bounds__(256) void conv1_kernel(const unsigned short* __restrict__ lowC,
                                                    const unsigned short* __restrict__ w1n,
                                                    const float* __restrict__ b_h,
                                                    unsigned short* __restrict__ outc) {
  __shared__ unsigned short Bl[64 * 128];
  int bid = blockIdx.x;
  int f = bid % 257, b = bid / 257;
  int tid = threadIdx.x;
  for (int i = tid; i < 1024; i += 256) {
    int row = i >> 4, c = i & 15;
    *(i32x4*)&Bl[row * 128 + ((c ^ (row & 7)) * 8)] = ((const i32x4*)w1n)[i];
  }
  __syncthreads();
  int lane = tid & 63, wv = tid >> 6;
  int lrow = lane & 15, q = lane >> 4;
  bf16x8 bf[4][4];
#pragma unroll
  for (int ks = 0; ks < 4; ks++)
#pragma unroll
    for (int nt = 0; nt < 4; nt++) {
      int rrow = nt * 16 + lrow;
      int c = ks * 4 + q;
      bf[ks][nt] = *(const bf16x8*)&Bl[rrow * 128 + ((c ^ (lrow & 7)) * 8)];
    }
  const unsigned short* lrowp = lowC + ((size_t)(b * HCV + f + 8)) * TCV * 16;
  unsigned short* orow = outc + ((size_t)(b * HCV + f + 8)) * FROW;
  float bv[4];
#pragma unroll
  for (int nt = 0; nt < 4; nt++) bv[nt] = b_h[nt * 16 + lrow];

  for (int tile = 0; tile < 5; tile++) {
    if (tile == 4 && wv != 0) break;
    int tbase = (tile < 4) ? (wv * 64 + tile * 16) : 256;
    f32x4 acc[4] = {f32x4{0,0,0,0}, f32x4{0,0,0,0}, f32x4{0,0,0,0}, f32x4{0,0,0,0}};
    const unsigned short* ap = lrowp + (size_t)(tbase + lrow + 5) * 16;
#pragma unroll
    for (int ks = 0; ks < 4; ks++) {
      bf16x8 a = *(const bf16x8*)&ap[ks * 32 + q * 8];
#pragma unroll
      for (int nt = 0; nt < 4; nt++)
        acc[nt] = __builtin_amdgcn_mfma_f32_16x16x32_bf16(a, bf[ks][nt], acc[nt], 0, 0, 0);
    }
    int tb = tbase + q * 4;
#pragma unroll
    for (int rg = 0; rg < 4; rg++) {
      int t = tb + rg;
      if (t < 257) {
#pragma unroll
        for (int nt = 0; nt < 4; nt++) {
          int oc = nt * 16 + lrow;
          float v = acc[nt][rg] + bv[nt];
          v = v > 0.f ? v : 0.2f * v;
          orow[(size_t)(nt >> 1) * PLANE + (size_t)(t + 8) * 32 + ((nt & 1) * 16 + lrow)] = f2bf(v);
        }
      }
    }
  }
}

// ---------------------------------------------------------------------------
// Dilated 3x3 conv 64->64 + bias + leaky.  Both operands in LDS, ks-split:
// 6 phases (kh x ks), LDS/block = Xs 17.1KB + Wl 12KB = 29.8KB -> 4 blk/CU.
// Staging is LINEAR copies (plane canvas + fragment-major weights);
// B ds_reads = lane*16B (bank-even, no swizzle); A ds_reads bank-even too.
// Main blocks [0,1032): bid&7 -> (b = g>>1, fh = g&1), f = fh*129+(bid>>3).
// Blocks [1032,1289): edge path (t=256), wave wv = batch, uses wln.
// ---------------------------------------------------------------------------
__global__ __launch_bounds__(256, 4) void conv3_kernel(const unsigned short* __restrict__ inc,
                                                       const unsigned short* __restrict__ wln,
                                                       const unsigned short* __restrict__ wfrag,
                                                       const float* __restrict__ bias,
                                                       unsigned short* __restrict__ outc,
                                                       int d) {
  __shared__ unsigned short Xs[273 * 32];      // one ks plane of the row
  __shared__ unsigned short Wl[3 * 4 * 512];   // [kw][nt][lane*8] frag-major
  int bid = blockIdx.x;
  int tid = threadIdx.x;
  int lane = tid & 63, wv = tid >> 6;

  if (bid >= 1032) {
    // ---- edge path: t = 256; wave wv = batch ----
    int f = bid - 1032;
    int b = wv;
    int oc = lane;
    float acc = 0.f;
#pragma unroll
    for (int tap = 0; tap < 9; tap++) {
      int kh = tap / 3, kw = tap - kh * 3;
      int row = f + 8 + (kh - 1) * d;
      int ct = 264 + (kw - 1) * d;
      const unsigned short* wp = &wln[(size_t)(tap * 64 + oc) * 64];
      for (int icq = 0; icq < 8; icq++) {
        const unsigned short* xp =
            &inc[((((size_t)b * HCV + row) * 2 + (icq >> 2)) * TCV + ct) * 32 + (icq & 3) * 8];
        i32x4 xv = *(const i32x4*)xp;
        i32x4 wq = *(const i32x4*)&wp[icq * 8];
#pragma unroll
        for (int j = 0; j < 4; j++)
          acc += bflo(xv[j]) * bflo(wq[j]) + bfhi(xv[j]) * bfhi(wq[j]);
      }
    }
    acc += bias[oc];
    acc = acc > 0.f ? acc : 0.2f * acc;
    outc[((((size_t)b * HCV + f + 8) * 2) * TCV + 264) * 32 + (oc & 31)
         + (size_t)(oc >> 5) * PLANE] = f2bf(acc);
    return;
  }

  int g = bid & 7;
  int b = g >> 1, fh = g & 1;
  int f = fh * 129 + (bid >> 3);
  if (f > 256) return;                        // 4 spill blocks (fh=1, fi=128)
  int lrow = lane & 15, q = lane >> 4;

  f32x4 acc[4][4];   // [mt][nt]
#pragma unroll
  for (int mt = 0; mt < 4; mt++)
#pragma unroll
    for (int nt = 0; nt < 4; nt++) acc[mt][nt] = f32x4{0,0,0,0};

  const size_t brow = (size_t)b * HCV;
  const int tbase0 = wv * 64;                 // wave's M-base in t (out t in [0,256))
#pragma unroll
  for (int kh = 0; kh < 3; kh++) {
#pragma unroll
    for (int ks = 0; ks < 2; ks++) {
      if (kh | ks) __syncthreads();           // prior phase's LDS reads done
      // stage X plane: 1092 i32x4, linear
      const i32x4* xsrc = (const i32x4*)(inc
          + ((brow + f + 8 + (kh - 1) * d) * 2 + ks) * (size_t)PLANE);
      for (int i = tid; i < 1092; i += 256) ((i32x4*)Xs)[i] = xsrc[i];
      // stage W slab: 3 taps x 256 i32x4, linear per tap
      for (int i = tid; i < 768; i += 256) {
        int t3 = i >> 8, j = i & 255;
        int tap = kh * 3 + t3;
        ((i32x4*)Wl)[t3 * 256 + j] =
            ((const i32x4*)(wfrag + (size_t)((tap * 2 + ks) * 4) * 512))[j];
      }
      __syncthreads();
#pragma unroll
      for (int kw = 0; kw < 3; kw++) {
        int tshift = 8 + (kw - 1) * d;        // input col for output t=0
        bf16x8 av[4];
#pragma unroll
        for (int mt = 0; mt < 4; mt++) {
          int t = tshift + tbase0 + mt * 16 + lrow;
          av[mt] = *(const bf16x8*)&Xs[t * 32 + q * 8];
        }
        bf16x8 bb[4];
#pragma unroll
        for (int nt = 0; nt < 4; nt++)
          bb[nt] = *(const bf16x8*)&Wl[(kw * 4 + nt) * 512 + lane * 8];
#pragma unroll
        for (int nt = 0; nt < 4; nt++)
#pragma unroll
          for (int mt = 0; mt < 4; mt++)
            acc[mt][nt] = __builtin_amdgcn_mfma_f32_16x16x32_bf16(av[mt], bb[nt], acc[mt][nt], 0, 0, 0);
      }
    }
  }

  unsigned short* orow = outc + (brow + f + 8) * (size_t)FROW;
#pragma unroll
  for (int mt = 0; mt < 4; mt++) {
    int tb = tbase0 + mt * 16 + q * 4;
#pragma unroll
    for (int rg = 0; rg < 4; rg++) {
      int t = tb + rg + 8;
#pragma unroll
      for (int nt = 0; nt < 4; nt++) {
        int oc = nt * 16 + lrow;
        float v = acc[mt][nt][rg] + bias[oc];
        v = v > 0.f ? v : 0.2f * v;
        orow[(size_t)(nt >> 1) * PLANE + (size_t)t * 32 + ((nt & 1) * 16 + lrow)] = f2bf(v);
      }
    }
  }
}

// Last conv 64->1, 3x3, pad 1, fp32 weights, writes d_out.  Plane canvas.
__global__ __launch_bounds__(256) void last_kernel(const unsigned short* __restrict__ inc,
                                                   const float* __restrict__ wlast,
                                                   const float* __restrict__ b_last,
                                                   float* __restrict__ out) {
  int idx = blockIdx.x * 256 + threadIdx.x;
  if (idx >= 4 * 66049) return;
  int b = idx / 66049, r = idx % 66049, f = r / 257, t = r % 257;
  float acc = b_last[0];
#pragma unroll
  for (int kh = 0; kh < 3; kh++) {
#pragma unroll
    for (int kw = 0; kw < 3; kw++) {
      const float* wp = &wlast[(kh * 3 + kw) * 64];
      size_t rbase = ((size_t)b * HCV + f + 8 + kh - 1) * FROW;
      for (int icq = 0; icq < 8; icq++) {
        const unsigned short* xp = &inc[rbase + (size_t)(icq >> 2) * PLANE
                                        + (size_t)(t + 8 + kw - 1) * 32 + (icq & 3) * 8];
        i32x4 xv = *(const i32x4*)xp;
#pragma unroll
        for (int j = 0; j < 4; j++) {
          acc += bflo(xv[j]) * wp[icq * 8 + 2 * j] + bfhi(xv[j]) * wp[icq * 8 + 2 * j + 1];
        }
      }
    }
  }
  out[idx] = acc;
}

extern "C" void kernel_launch(void* const* d_in, const int* in_sizes, int n_in,
                              void* d_out, int out_size, void* d_ws, size_t ws_size,
                              hipStream_t stream) {
  const float* x      = (const float*)d_in[0];
  const float* v_h    = (const float*)d_in[1];
  const float* g_h    = (const float*)d_in[2];
  const float* b_h    = (const float*)d_in[3];
  const float* vs     = (const float*)d_in[4];
  const float* gs     = (const float*)d_in[5];
  const float* bs     = (const float*)d_in[6];
  const float* v_last = (const float*)d_in[7];
  const float* g_last = (const float*)d_in[8];
  const float* b_last = (const float*)d_in[9];

  char* ws = (char*)d_ws;
  unsigned short* canvasA = (unsigned short*)ws;
  unsigned short* canvasB = (unsigned short*)(ws + CAN_BYTES);
  unsigned short* lowC    = canvasB;                         // aliased; re-zeroed after conv1
  float*          spec    = (float*)(ws + 2 * CAN_BYTES);
  unsigned short* w1n     = (unsigned short*)(ws + 2 * CAN_BYTES + SPEC_BYTES);
  unsigned short* wln     = (unsigned short*)(ws + 2 * CAN_BYTES + SPEC_BYTES + W1N_BYTES);
  unsigned short* wfrag   = (unsigned short*)(ws + 2 * CAN_BYTES + SPEC_BYTES + W1N_BYTES + WLN_BYTES);
  float*          wlast   = (float*)(ws + 2 * CAN_BYTES + SPEC_BYTES + W1N_BYTES + WLN_BYTES + WFRAG_BYTES);
  float*          out     = (float*)d_out;

  halo_zero_kernel<<<(NBATCH * HCV * TCV + 255) / 256, 256, 0, stream>>>(canvasA, canvasB, lowC);
  wnorm_kernel<<<577, 256, 0, stream>>>(v_h, g_h, vs, gs, v_last, g_last, w1n, wln, wfrag, wlast);
  stft_kernel<<<4 * 257, 256, 0, stream>>>(x, spec);
  lower_kernel<<<(4 * 66049 + 255) / 256, 256, 0, stream>>>(spec, lowC);
  conv1_kernel<<<4 * 257, 256, 0, stream>>>(lowC, w1n, b_h, canvasA);

  // lowC occupied canvasB's first bytes: restore zeros (halo incl.) before
  // layer 1 writes canvasB
  hipMemsetAsync(canvasB, 0, LOWC_BYTES, stream);

  unsigned short* cur = canvasA;
  unsigned short* nxt = canvasB;
  for (int l = 0; l < 8; l++) {
    int d = l + 1;
    const unsigned short* w  = wln + (size_t)l * 9 * 64 * 64;
    const unsigned short* wf = wfrag + (size_t)l * 36864;
    const float* bb = bs + l * 64;
    conv3_kernel<<<1032 + 257, 256, 0, stream>>>(cur, w, wf, bb, nxt, d);
    unsigned short* tmp = cur; cur = nxt; nxt = tmp;
  }

  last_kernel<<<(4 * 66049 + 255) / 256, 256, 0, stream>>>(cur, wlast, b_last, out);
}

// Round 15
// 476.323 us; speedup vs baseline: 1.2416x; 1.2416x over previous
//
#include <hip/hip_runtime.h>
#include <stdint.h>

// ---------------------------------------------------------------------------
// HarmonicStructureDiscriminator on MI355X (gfx950)
// STFT(512/256) -> log-shift lower (KF=7) -> conv1x7(14->64)
//   -> 8x dilated conv3x3(64->64, d=1..8) -> conv3x3(64->1)
// Round 15 = R14 with the staging-width bug fixed (each 8KB W slab = 512
// i32x4 -> 2 per thread; R14 only copied 256, leaving ks=1 uninitialized).
// Design: R12 both-in-LDS (56.2us, FETCH 19MB, 0 conflicts measured) + W
// phased per-tap via double-buffered 2x8KB fragment-major slabs -> LDS
// 50.1KB -> 3 blocks/CU; edge blocks first (no scalar tail).
// mfma_f32_16x16x32_bf16: A[m=lane&15][k=q*8+j], B[n=lane&15][k],
// D col=lane&15,row=q*4+reg (m89/m101-verified).
// ---------------------------------------------------------------------------

typedef __attribute__((ext_vector_type(8))) short bf16x8;
typedef __attribute__((ext_vector_type(4))) float f32x4;
typedef __attribute__((ext_vector_type(4))) int   i32x4;

#define HCV 273
#define TCV 273
#define NBATCH 4

static constexpr size_t CAN_BYTES  = (size_t)NBATCH * HCV * TCV * 64 * 2;  // 38,158,848
static constexpr size_t LOWC_BYTES = (size_t)NBATCH * HCV * TCV * 16 * 2;  // 9,539,712
static constexpr size_t SPEC_BYTES = (size_t)NBATCH * 257 * 257 * 2 * 4;
static constexpr size_t W1N_BYTES  = 64 * 128 * 2;
static constexpr size_t WLN_BYTES  = 8 * 9 * 64 * 64 * 2;
static constexpr size_t WFRAG_BYTES = 8 * 9 * 2 * 4 * 512 * 2;             // 589,824

static __device__ __forceinline__ unsigned short f2bf(float f) {
  union { float f; unsigned u; } v; v.f = f;
  unsigned r = v.u + 0x7FFFu + ((v.u >> 16) & 1u);   // RNE
  return (unsigned short)(r >> 16);
}
static __device__ __forceinline__ float bflo(int u) {
  union { unsigned u; float f; } v; v.u = ((unsigned)u) << 16; return v.f;
}
static __device__ __forceinline__ float bfhi(int u) {
  union { unsigned u; float f; } v; v.u = ((unsigned)u) & 0xFFFF0000u; return v.f;
}

// ---------------------------------------------------------------------------
// Zero ONLY the canvas halos (interior is fully overwritten each layer).
// 64-channel canvas [b][f][t][64].
// ---------------------------------------------------------------------------
__global__ __launch_bounds__(256) void halo_zero_kernel(unsigned short* cA,
                                                        unsigned short* cB,
                                                        unsigned short* lowC) {
  int idx = blockIdx.x * 256 + threadIdx.x;
  if (idx >= NBATCH * HCV * TCV) return;
  int pos = idx % (HCV * TCV);
  int row = pos / TCV, col = pos % TCV;
  bool halo = (row < 8) | (row > 264) | (col < 8) | (col > 264);
  if (!halo) return;
  i32x4 z = {0, 0, 0, 0};
  i32x4* a = (i32x4*)(cA + (size_t)idx * 64);
  i32x4* b = (i32x4*)(cB + (size_t)idx * 64);
#pragma unroll
  for (int i = 0; i < 8; i++) { a[i] = z; b[i] = z; }
  i32x4* l = (i32x4*)(lowC + (size_t)idx * 16);
  l[0] = z; l[1] = z;
}

// ---------------------------------------------------------------------------
// Weight normalization.
// blocks 0..63:   conv1 -> w1n[oc][k], k = kw*16+ch
// blocks 64..575: 8 layers x 64 oc -> wln[l][tap][oc][ic]  (edge path)
//                 AND wfrag fragment-major: [l][tap][ks][nt][lane][j]
// block 576:      last conv -> fp32 wlast[tap][ic]
// ---------------------------------------------------------------------------
__global__ __launch_bounds__(256) void wnorm_kernel(
    const float* v_h, const float* g_h,
    const float* vs, const float* gs,
    const float* v_last, const float* g_last,
    unsigned short* w1n, unsigned short* wln, unsigned short* wfrag,
    float* wlast) {
  __shared__ float red[256];
  int bid = blockIdx.x, tid = threadIdx.x;
  if (bid < 64) {
    int oc = bid;
    const float* v = v_h + oc * 98;       // [ch][kw] = [14][7]
    float s = 0.f;
    for (int i = tid; i < 98; i += 256) s += v[i] * v[i];
    red[tid] = s; __syncthreads();
    for (int off = 128; off > 0; off >>= 1) { if (tid < off) red[tid] += red[tid + off]; __syncthreads(); }
    float scale = g_h[oc] / sqrtf(red[0]);
    for (int k = tid; k < 128; k += 256) {
      int kw = k >> 4, ch = k & 15;
      unsigned short val = 0;
      if (kw < 7 && ch < 14) val = f2bf(v[ch * 7 + kw] * scale);
      w1n[oc * 128 + k] = val;
    }
  } else if (bid < 576) {
    int l = (bid - 64) >> 6, oc = (bid - 64) & 63;
    const float* v = vs + ((size_t)(l * 64 + oc)) * 576;  // [ic][kh][kw]
    float s = 0.f;
    for (int i = tid; i < 576; i += 256) s += v[i] * v[i];
    red[tid] = s; __syncthreads();
    for (int off = 128; off > 0; off >>= 1) { if (tid < off) red[tid] += red[tid + off]; __syncthreads(); }
    float scale = gs[l * 64 + oc] / sqrtf(red[0]);
    int nt = oc >> 4, lr = oc & 15;
    for (int i = tid; i < 576; i += 256) {
      int ic = i / 9, tap = i - ic * 9;
      unsigned short val = f2bf(v[i] * scale);
      wln[(((size_t)l * 9 + tap) * 64 + oc) * 64 + ic] = val;
      int ks = ic >> 5, qq = (ic >> 3) & 3, j = ic & 7;
      wfrag[(size_t)l * 36864 + (((tap * 2 + ks) * 4 + nt) * 512)
            + (((qq << 4) | lr) * 8) + j] = val;
    }
  } else {
    const float* v = v_last;
    float s = 0.f;
    for (int i = tid; i < 576; i += 256) s += v[i] * v[i];
    red[tid] = s; __syncthreads();
    for (int off = 128; off > 0; off >>= 1) { if (tid < off) red[tid] += red[tid + off]; __syncthreads(); }
    float scale = g_last[0] / sqrtf(red[0]);
    for (int i = tid; i < 576; i += 256) {
      int ic = i / 9, tap = i - ic * 9;
      wlast[tap * 64 + ic] = v[i] * scale;
    }
  }
}

// ---------------------------------------------------------------------------
// STFT: radix-2 DIT FFT in LDS; reflect pad + Hann fused into bit-rev load.
// ---------------------------------------------------------------------------
__global__ __launch_bounds__(256) void stft_kernel(const float* __restrict__ x,
                                                   float* __restrict__ spec) {
  __shared__ float re[512];
  __shared__ float im[512];
  int bid = blockIdx.x;
  int b = bid / 257, fr = bid % 257;
  const float* xb = x + (size_t)b * 65536;
  int tid = threadIdx.x;
  for (int ii = 0; ii < 2; ii++) {
    int n = tid + ii * 256;
    int s = __brev((unsigned)n) >> 23;
    int j = fr * 256 + s - 256;
    int ja = j < 0 ? -j : (j >= 65536 ? 131070 - j : j);
    float w = 0.5f - 0.5f * __cosf(6.283185307179586f * (float)s / 512.0f);
    re[n] = xb[ja] * w;
    im[n] = 0.f;
  }
  __syncthreads();
  for (int st = 0; st < 9; st++) {
    int half = 1 << st;
    int p = tid & (half - 1);
    int g = tid >> st;
    int i0 = (g << (st + 1)) + p;
    int i1 = i0 + half;
    float ang = -6.283185307179586f * (float)p / (float)(2 << st);
    float sv, cv; __sincosf(ang, &sv, &cv);
    float br = re[i1], bi = im[i1];
    float tr = cv * br - sv * bi;
    float ti = cv * bi + sv * br;
    float ar = re[i0], ai = im[i0];
    re[i1] = ar - tr; im[i1] = ai - ti;
    re[i0] = ar + tr; im[i0] = ai + ti;
    __syncthreads();
  }
  for (int k = tid; k < 257; k += 256) {
    float* o = spec + (((size_t)b * 257 + fr) * 257 + k) * 2;
    o[0] = re[k];
    o[1] = im[k];
  }
}

// ---------------------------------------------------------------------------
// Harmonic lowering -> lowC canvas [b][f+8][t+8][16] (ch14,15 = 0), bf16.
// ---------------------------------------------------------------------------
__global__ __launch_bounds__(256) void lower_kernel(const float* __restrict__ spec,
                                                    unsigned short* __restrict__ lowC) {
  int idx = blockIdx.x * 256 + threadIdx.x;
  if (idx >= 4 * 66049) return;
  int b = idx / 66049, r = idx % 66049, f = r / 257, t = r % 257;
  const float shifts[7] = {1945.9101090932196f, 1252.7629684953681f, 847.2978603872037f,
                           559.6157879354227f, 336.4722366212129f, 154.15067982725836f, 0.0f};
  const float* sp = spec + ((size_t)(b * 257 + t)) * 257 * 2;
  unsigned short* lp = lowC + (((size_t)b * HCV + f + 8) * TCV + t + 8) * 16;
  unsigned w[8];
  for (int kf = 0; kf < 7; kf++) {
    float src = (float)f - shifts[kf];
    float lo = floorf(src);
    int li = (int)lo;
    float fr = src - lo;
    float g0r = 0.f, g0i = 0.f, g1r = 0.f, g1i = 0.f;
    if (li >= 0 && li < 257) { g0r = sp[li * 2]; g0i = sp[li * 2 + 1]; }
    if (li + 1 >= 0 && li + 1 < 257) { g1r = sp[(li + 1) * 2]; g1i = sp[(li + 1) * 2 + 1]; }
    float vr = (1.f - fr) * g0r + fr * g1r;
    float vi = (1.f - fr) * g0i + fr * g1i;
    w[kf] = (unsigned)f2bf(vr) | ((unsigned)f2bf(vi) << 16);
  }
  w[7] = 0;
  ((i32x4*)lp)[0] = i32x4{(int)w[0], (int)w[1], (int)w[2], (int)w[3]};
  ((i32x4*)lp)[1] = i32x4{(int)w[4], (int)w[5], (int)w[6], (int)w[7]};
}

// ---------------------------------------------------------------------------
// conv1: 14->64, 1x7, pad 3.  Block = (b,f) row.  B in registers (from
// swizzled LDS), A direct from global (im2col rows contiguous in NHWC16).
// Writes 64-channel canvas.
// ---------------------------------------------------------------------------
__global__ __launch_bounds__(256) void conv1_kernel(const unsigned short* __restrict__ lowC,
                                                    const unsigned short* __restrict__ w1n,
                                                    const float* __restrict__ b_h,
                                                    unsigned short* __restrict__ outc) {
  __shared__ unsigned short Bl[64 * 128];
  int bid = blockIdx.x;
  int f = bid % 257, b = bid / 257;
  int tid = threadIdx.x;
  for (int i = tid; i < 1024; i += 256) {
    int row = i >> 4, c = i & 15;
    *(i32x4*)&Bl[row * 128 + ((c ^ (row & 7)) * 8)] = ((const i32x4*)w1n)[i];
  }
  __syncthreads();
  int lane = tid & 63, wv = tid >> 6;
  int lrow = lane & 15, q = lane >> 4;
  bf16x8 bf[4][4];
#pragma unroll
  for (int ks = 0; ks < 4; ks++)
#pragma unroll
    for (int nt = 0; nt < 4; nt++) {
      int rrow = nt * 16 + lrow;
      int c = ks * 4 + q;
      bf[ks][nt] = *(const bf16x8*)&Bl[rrow * 128 + ((c ^ (lrow & 7)) * 8)];
    }
  const unsigned short* lrowp = lowC + ((size_t)(b * HCV + f + 8)) * TCV * 16;
  unsigned short* orow = outc + ((size_t)(b * HCV + f + 8)) * TCV * 64;
  float bv[4];
#pragma unroll
  for (int nt = 0; nt < 4; nt++) bv[nt] = b_h[nt * 16 + lrow];

  for (int tile = 0; tile < 5; tile++) {
    if (tile == 4 && wv != 0) break;
    int tbase = (tile < 4) ? (wv * 64 + tile * 16) : 256;
    f32x4 acc[4] = {f32x4{0,0,0,0}, f32x4{0,0,0,0}, f32x4{0,0,0,0}, f32x4{0,0,0,0}};
    const unsigned short* ap = lrowp + (size_t)(tbase + lrow + 5) * 16;
#pragma unroll
    for (int ks = 0; ks < 4; ks++) {
      bf16x8 a = *(const bf16x8*)&ap[ks * 32 + q * 8];
#pragma unroll
      for (int nt = 0; nt < 4; nt++)
        acc[nt] = __builtin_amdgcn_mfma_f32_16x16x32_bf16(a, bf[ks][nt], acc[nt], 0, 0, 0);
    }
    int tb = tbase + q * 4;
#pragma unroll
    for (int rg = 0; rg < 4; rg++) {
      int t = tb + rg;
      if (t < 257) {
#pragma unroll
        for (int nt = 0; nt < 4; nt++) {
          int oc = nt * 16 + lrow;
          float v = acc[nt][rg] + bv[nt];
          v = v > 0.f ? v : 0.2f * v;
          orow[(size_t)(t + 8) * 64 + oc] = f2bf(v);
        }
      }
    }
  }
}

// ---------------------------------------------------------------------------
// Dilated 3x3 conv 64->64 + bias + leaky.  Both operands in LDS.
// Blocks [0,257): edge path (t=256), wave wv = batch  -- first, no tail.
// Blocks [257, 257+1032): main.  (bid-257)&7 -> (b, fh), f = fh*129 + rest.
//   Per kh: stage X row (273x64, 34.9KB, XOR-swizzled) once; W phased
//   per-tap through double-buffered 2x8KB fragment-major slabs (512 i32x4
//   each = 2 per thread).  LDS 50.1KB -> 3 blocks/CU.  Wave M=64, N=64.
// ---------------------------------------------------------------------------
__global__ __launch_bounds__(256, 3) void conv3_kernel(const unsigned short* __restrict__ inc,
                                                       const unsigned short* __restrict__ wln,
                                                       const unsigned short* __restrict__ wfrag,
                                                       const float* __restrict__ bias,
                                                       unsigned short* __restrict__ outc,
                                                       int d) {
  __shared__ unsigned short Xs[273 * 64];      // 34.9KB, XOR-chunk swizzled
  __shared__ unsigned short Wl[2][4096];       // 2 x 8KB frag-major W slabs
  int bid = blockIdx.x;
  int tid = threadIdx.x;
  int lane = tid & 63, wv = tid >> 6;

  if (bid < 257) {
    // ---- edge path: t = 256; wave wv = batch ----
    int f = bid;
    int b = wv;
    int oc = lane;
    float acc = 0.f;
#pragma unroll
    for (int tap = 0; tap < 9; tap++) {
      int kh = tap / 3, kw = tap - kh * 3;
      int row = f + 8 + (kh - 1) * d;
      int ct = 264 + (kw - 1) * d;
      const unsigned short* xp = &inc[(((size_t)b * HCV + row) * TCV + ct) * 64];
      const unsigned short* wp = &wln[(size_t)(tap * 64 + oc) * 64];
      for (int icq = 0; icq < 8; icq++) {
        i32x4 xv = *(const i32x4*)&xp[icq * 8];
        i32x4 wq = *(const i32x4*)&wp[icq * 8];
#pragma unroll
        for (int j = 0; j < 4; j++)
          acc += bflo(xv[j]) * bflo(wq[j]) + bfhi(xv[j]) * bfhi(wq[j]);
      }
    }
    acc += bias[oc];
    acc = acc > 0.f ? acc : 0.2f * acc;
    outc[(((size_t)b * HCV + f + 8) * TCV + 264) * 64 + oc] = f2bf(acc);
    return;
  }

  int mb = bid - 257;
  int g = mb & 7;
  int b = g >> 1, fh = g & 1;
  int f = fh * 129 + (mb >> 3);
  if (f > 256) return;                        // 4 spill blocks (fh=1, fi=128)
  int lrow = lane & 15, q = lane >> 4;

  f32x4 acc[4][4];   // [mt][nt]
#pragma unroll
  for (int mt = 0; mt < 4; mt++)
#pragma unroll
    for (int nt = 0; nt < 4; nt++) acc[mt][nt] = f32x4{0,0,0,0};

  const size_t brow = (size_t)b * HCV;
  const int tbase0 = wv * 64;                 // wave's M-base in t (0..255 out)
#pragma unroll
  for (int kh = 0; kh < 3; kh++) {
    if (kh) __syncthreads();                  // prior phase's LDS reads done
    // stage input row (273 x 64ch): 2184 i32x4, coalesced, XOR-swizzled
    const i32x4* rowp = (const i32x4*)(inc + (brow + f + 8 + (kh - 1) * d) * TCV * 64);
    for (int i = tid; i < 2184; i += 256) {
      int t = i >> 3, c = i & 7;
      *(i32x4*)&Xs[t * 64 + ((c ^ (t & 7)) * 8)] = rowp[i];
    }
    // stage W slab for kw=0 into buffer 0: 512 i32x4 = 2 per thread
    {
      const i32x4* wsrc = (const i32x4*)(wfrag + (size_t)((kh * 3 + 0) * 8) * 512);
      ((i32x4*)&Wl[0][0])[tid] = wsrc[tid];
      ((i32x4*)&Wl[0][0])[tid + 256] = wsrc[tid + 256];
    }
    __syncthreads();
#pragma unroll
    for (int kw = 0; kw < 3; kw++) {
      int buf = kw & 1;
      // prefetch next tap's W slab into the other buffer (its readers all
      // finished before the barrier that opened this section)
      if (kw < 2) {
        const i32x4* wsrc = (const i32x4*)(wfrag + (size_t)((kh * 3 + kw + 1) * 8) * 512);
        ((i32x4*)&Wl[buf ^ 1][0])[tid] = wsrc[tid];
        ((i32x4*)&Wl[buf ^ 1][0])[tid + 256] = wsrc[tid + 256];
      }
      int tshift = 8 + (kw - 1) * d;          // input col for output t=0
#pragma unroll
      for (int ks = 0; ks < 2; ks++) {
        bf16x8 bb[4];
#pragma unroll
        for (int nt = 0; nt < 4; nt++)
          bb[nt] = *(const bf16x8*)&Wl[buf][(ks * 4 + nt) * 512 + lane * 8];
        bf16x8 av[4];
#pragma unroll
        for (int mt = 0; mt < 4; mt++) {
          int t = tshift + tbase0 + mt * 16 + lrow;
          av[mt] = *(const bf16x8*)&Xs[t * 64 + (((ks * 4 + q) ^ (t & 7)) * 8)];
        }
#pragma unroll
        for (int nt = 0; nt < 4; nt++)
#pragma unroll
          for (int mt = 0; mt < 4; mt++)
            acc[mt][nt] = __builtin_amdgcn_mfma_f32_16x16x32_bf16(av[mt], bb[nt], acc[mt][nt], 0, 0, 0);
      }
      if (kw < 2) __syncthreads();            // W slab ready / readers done
    }
  }

  unsigned short* orow = outc + ((brow + f + 8) * TCV + 8) * 64;
#pragma unroll
  for (int mt = 0; mt < 4; mt++) {
    int tb = tbase0 + mt * 16 + q * 4;
#pragma unroll
    for (int rg = 0; rg < 4; rg++) {
      int t = tb + rg;
#pragma unroll
      for (int nt = 0; nt < 4; nt++) {   // nt innermost: 4x32B of one 128B row
        int oc = nt * 16 + lrow;
        float v = acc[mt][nt][rg] + bias[oc];
        v = v > 0.f ? v : 0.2f * v;
        orow[(size_t)t * 64 + oc] = f2bf(v);
      }
    }
  }
}

// Last conv 64->1, 3x3, pad 1, fp32 weights, writes d_out.  64ch canvas.
__global__ __launch_bounds__(256) void last_kernel(const unsigned short* __restrict__ inc,
                                                   const float* __restrict__ wlast,
                                                   const float* __restrict__ b_last,
                                                   float* __restrict__ out) {
  int idx = blockIdx.x * 256 + threadIdx.x;
  if (idx >= 4 * 66049) return;
  int b = idx / 66049, r = idx % 66049, f = r / 257, t = r % 257;
  float acc = b_last[0];
#pragma unroll
  for (int kh = 0; kh < 3; kh++) {
#pragma unroll
    for (int kw = 0; kw < 3; kw++) {
      const unsigned short* xp = &inc[(((size_t)b * HCV + f + 8 + kh - 1) * TCV + t + 8 + kw - 1) * 64];
      const float* wp = &wlast[(kh * 3 + kw) * 64];
      for (int icq = 0; icq < 8; icq++) {
        i32x4 xv = *(const i32x4*)&xp[icq * 8];
#pragma unroll
        for (int j = 0; j < 4; j++) {
          acc += bflo(xv[j]) * wp[icq * 8 + 2 * j] + bfhi(xv[j]) * wp[icq * 8 + 2 * j + 1];
        }
      }
    }
  }
  out[idx] = acc;
}

extern "C" void kernel_launch(void* const* d_in, const int* in_sizes, int n_in,
                              void* d_out, int out_size, void* d_ws, size_t ws_size,
                              hipStream_t stream) {
  const float* x      = (const float*)d_in[0];
  const float* v_h    = (const float*)d_in[1];
  const float* g_h    = (const float*)d_in[2];
  const float* b_h    = (const float*)d_in[3];
  const float* vs     = (const float*)d_in[4];
  const float* gs     = (const float*)d_in[5];
  const float* bs     = (const float*)d_in[6];
  const float* v_last = (const float*)d_in[7];
  const float* g_last = (const float*)d_in[8];
  const float* b_last = (const float*)d_in[9];

  char* ws = (char*)d_ws;
  unsigned short* canvasA = (unsigned short*)ws;
  unsigned short* canvasB = (unsigned short*)(ws + CAN_BYTES);
  unsigned short* lowC    = canvasB;                         // aliased; re-zeroed after conv1
  float*          spec    = (float*)(ws + 2 * CAN_BYTES);
  unsigned short* w1n     = (unsigned short*)(ws + 2 * CAN_BYTES + SPEC_BYTES);
  unsigned short* wln     = (unsigned short*)(ws + 2 * CAN_BYTES + SPEC_BYTES + W1N_BYTES);
  unsigned short* wfrag   = (unsigned short*)(ws + 2 * CAN_BYTES + SPEC_BYTES + W1N_BYTES + WLN_BYTES);
  float*          wlast   = (float*)(ws + 2 * CAN_BYTES + SPEC_BYTES + W1N_BYTES + WLN_BYTES + WFRAG_BYTES);
  float*          out     = (float*)d_out;

  halo_zero_kernel<<<(NBATCH * HCV * TCV + 255) / 256, 256, 0, stream>>>(canvasA, canvasB, lowC);
  wnorm_kernel<<<577, 256, 0, stream>>>(v_h, g_h, vs, gs, v_last, g_last, w1n, wln, wfrag, wlast);
  stft_kernel<<<4 * 257, 256, 0, stream>>>(x, spec);
  lower_kernel<<<(4 * 66049 + 255) / 256, 256, 0, stream>>>(spec, lowC);
  conv1_kernel<<<4 * 257, 256, 0, stream>>>(lowC, w1n, b_h, canvasA);

  // lowC occupied canvasB's first bytes: restore zeros (halo incl.) before
  // layer 1 writes canvasB
  hipMemsetAsync(canvasB, 0, LOWC_BYTES, stream);

  unsigned short* cur = canvasA;
  unsigned short* nxt = canvasB;
  for (int l = 0; l < 8; l++) {
    int d = l + 1;
    const unsigned short* w  = wln + (size_t)l * 9 * 64 * 64;
    const unsigned short* wf = wfrag + (size_t)l * 36864;
    const float* bb = bs + l * 64;
    conv3_kernel<<<257 + 1032, 256, 0, stream>>>(cur, w, wf, bb, nxt, d);
    unsigned short* tmp = cur; cur = nxt; nxt = tmp;
  }

  last_kernel<<<(4 * 66049 + 255) / 256, 256, 0, stream>>>(cur, wlast, b_last, out);
}